// Round 1
// 266.262 us; speedup vs baseline: 1.0317x; 1.0317x over previous
//
#include <hip/hip_runtime.h>
#include <hip/hip_bf16.h>

// Problem constants (B=4, N=4096, D=1024, H=16, hd=64, G=512, sigma=3)
#define NPOS 4096
#define DIM  1024
#define GSZ  512

#define GAS __attribute__((address_space(1)))
#define LAS __attribute__((address_space(3)))

typedef __attribute__((ext_vector_type(8))) short bf16x8;   // 8 bf16 (4 VGPRs)
typedef __attribute__((ext_vector_type(4))) float f32x4;

__device__ __forceinline__ void async_load16(const void* g, void* l) {
  __builtin_amdgcn_global_load_lds((const GAS void*)g, (LAS void*)l, 16, 0, 0);
}

// Bit-exact replica of np: (arange(N,f32)/4095)*511 then trunc-to-int32.
__device__ __forceinline__ int fidx_of(int n) {
  return (int)(((float)n / 4095.0f) * 511.0f);
}

__device__ __forceinline__ float bf2f(unsigned short s) {
  union { unsigned u; float f; } v; v.u = ((unsigned)s) << 16; return v.f;
}

// exact [i0,i1) row-range of bin g under fidx_of
// NOTE: bins are 8 or 9 rows EXCEPT bin 511 which has exactly 1 row (n=4095).
__device__ __forceinline__ void bin_range(int g, int& i0, int& i1) {
  i0 = (g * 4095 + 510) / 511;
  while (i0 > 0 && fidx_of(i0 - 1) >= g) --i0;
  while (i0 < NPOS && fidx_of(i0) < g) ++i0;
  if (g == GSZ - 1) { i1 = NPOS; return; }
  i1 = ((g + 1) * 4095 + 510) / 511;
  while (i1 > 0 && fidx_of(i1 - 1) >= g + 1) --i1;
  while (i1 < NPOS && fidx_of(i1) < g + 1) ++i1;
}

// ---------------- all f32->bf16 casts in one launch (r9 config) ----------------
// blocks [0,16384): x ; [16384,17408): k_w ; [17408,18432): v_w ; [18432,19456): out_w
__global__ __launch_bounds__(256) void cast_all(
    const float* __restrict__ x, const float* __restrict__ kw,
    const float* __restrict__ vw, const float* __restrict__ ow,
    __hip_bfloat16* __restrict__ xb, __hip_bfloat16* __restrict__ kvwb,
    __hip_bfloat16* __restrict__ outwb) {
  int blk = blockIdx.x;
  const float* src; __hip_bfloat16* dst; int off;
  if (blk < 16384)      { src = x;  dst = xb;              off = blk; }
  else if (blk < 17408) { src = kw; dst = kvwb;            off = blk - 16384; }
  else if (blk < 18432) { src = vw; dst = kvwb + 1048576;  off = blk - 17408; }
  else                  { src = ow; dst = outwb;           off = blk - 18432; }
  int i = (off * 256 + threadIdx.x) * 4;
  float4 f = *(const float4*)(src + i);
  ushort4 o;
  __hip_bfloat16 t;
  t = __float2bfloat16(f.x); o.x = *(unsigned short*)&t;
  t = __float2bfloat16(f.y); o.y = *(unsigned short*)&t;
  t = __float2bfloat16(f.z); o.z = *(unsigned short*)&t;
  t = __float2bfloat16(f.w); o.w = *(unsigned short*)&t;
  *(ushort4*)(dst + i) = o;
}

// ---------------- fused K+V projection with in-epilogue K-norm reduction ----------------
// A: 16384 x 1024 (xb).  B: 2048 x 1024 row-major = [k_w ; v_w].
// Blocks with bn < 1024 compute K-tiles: they do NOT write K. Each wave's 64-col
// span (wn is 64-wide) is exactly one head, so ||k_row||^2 = sum over the wave's
// own accumulators: sum_nt (acc+k_b)^2, then shfl_xor-reduce over the 16 m16
// lanes of each quad. Writes knorm[row*16+head] (f32, 1 MB) instead of 32 MB bf16 K.
// Blocks with bn >= 1024 compute V-tiles and store bf16 into Vb (16384 x 1024).
// Main K-loop identical to the verified gemm_bt (m97 geometry, BK=64).
__global__ __launch_bounds__(256) void gemm_kv(
    const __hip_bfloat16* __restrict__ A,
    const __hip_bfloat16* __restrict__ B,
    const float* __restrict__ k_b, const float* __restrict__ v_b,
    __hip_bfloat16* __restrict__ Vb, float* __restrict__ knorm) {
  const int K = 1024;
  __shared__ __align__(16) __hip_bfloat16 As[2][128 * 32];
  __shared__ __align__(16) __hip_bfloat16 Bs[2][128 * 32];
  const int tid = threadIdx.x;
  const int bm = blockIdx.x * 128, bn = blockIdx.y * 128;

  const int srow = tid >> 2;          // 0..63
  const int scol = (tid & 3) * 8;     // 0,8,16,24
  const __hip_bfloat16* ap0 = A + (size_t)(bm + srow) * K + scol;
  const __hip_bfloat16* ap1 = A + (size_t)(bm + srow + 64) * K + scol;
  const __hip_bfloat16* bp0 = B + (size_t)(bn + srow) * K + scol;
  const __hip_bfloat16* bp1 = B + (size_t)(bn + srow + 64) * K + scol;
  const int soff = srow * 32 + scol;  // lane-ordered: tid*16B within each half

  const int wave = tid >> 6, lane = tid & 63;
  const int wm = (wave >> 1) * 64, wn = (wave & 1) * 64;
  const int m16 = lane & 15, quad = lane >> 4;

  f32x4 acc[4][4];
#pragma unroll
  for (int i = 0; i < 4; i++)
#pragma unroll
    for (int j = 0; j < 4; j++) acc[i][j] = (f32x4)0.f;

  for (int k0 = 0; k0 < K; k0 += 64) {
    // stage both 32-wide halves, then one barrier pair for 32 MFMAs
    async_load16(ap0 + k0, &As[0][soff]);
    async_load16(ap1 + k0, &As[0][soff + 64 * 32]);
    async_load16(bp0 + k0, &Bs[0][soff]);
    async_load16(bp1 + k0, &Bs[0][soff + 64 * 32]);
    async_load16(ap0 + k0 + 32, &As[1][soff]);
    async_load16(ap1 + k0 + 32, &As[1][soff + 64 * 32]);
    async_load16(bp0 + k0 + 32, &Bs[1][soff]);
    async_load16(bp1 + k0 + 32, &Bs[1][soff + 64 * 32]);
    __syncthreads();
#pragma unroll
    for (int h = 0; h < 2; h++) {
      bf16x8 af[4], bfr[4];
#pragma unroll
      for (int mt = 0; mt < 4; mt++)
        af[mt] = *(const bf16x8*)&As[h][(wm + mt * 16 + m16) * 32 + quad * 8];
#pragma unroll
      for (int nt = 0; nt < 4; nt++)
        bfr[nt] = *(const bf16x8*)&Bs[h][(wn + nt * 16 + m16) * 32 + quad * 8];
#pragma unroll
      for (int mt = 0; mt < 4; mt++)
#pragma unroll
        for (int nt = 0; nt < 4; nt++)
          acc[mt][nt] = __builtin_amdgcn_mfma_f32_16x16x32_bf16(af[mt], bfr[nt], acc[mt][nt], 0, 0, 0);
    }
    __syncthreads();
  }

  // epilogue: C/D layout col=lane&15, row=quad*4+reg (m89/m91-verified)
  if (bn < 1024) {
    // K block: reduce ||k||^2 per (row, head) entirely in-register/wave.
    const int head = (bn + wn) >> 6;
    float bv[4];
#pragma unroll
    for (int nt = 0; nt < 4; nt++) bv[nt] = k_b[bn + wn + nt * 16 + m16];
#pragma unroll
    for (int mt = 0; mt < 4; mt++) {
#pragma unroll
      for (int r = 0; r < 4; r++) {
        float s = 0.f;
#pragma unroll
        for (int nt = 0; nt < 4; nt++) {
          float v = acc[mt][nt][r] + bv[nt];
          s += v * v;
        }
        // reduce across the 16 m16-lanes of this quad (bits 0..3 of lane)
        s += __shfl_xor(s, 1);
        s += __shfl_xor(s, 2);
        s += __shfl_xor(s, 4);
        s += __shfl_xor(s, 8);
        if (m16 == 0) {
          int row = bm + wm + mt * 16 + quad * 4 + r;
          knorm[(size_t)row * 16 + head] = sqrtf(s);
        }
      }
    }
  } else {
    // V block: bf16 store into dedicated Vb (row stride 1024)
#pragma unroll
    for (int mt = 0; mt < 4; mt++) {
#pragma unroll
      for (int nt = 0; nt < 4; nt++) {
        int col = bn - 1024 + wn + nt * 16 + m16;
        float bv = v_b[col];
#pragma unroll
        for (int r = 0; r < 4; r++) {
          int row = bm + wm + mt * 16 + quad * 4 + r;
          Vb[(size_t)row * 1024 + col] = __float2bfloat16(acc[mt][nt][r] + bv);
        }
      }
    }
  }
}

// ---------------- dedup output GEMM: outc = conv @ outw^T + bias (f32) ----------------
// M=2048, N=1024, K=1024. 64x64 tiles -> grid (32,16) = 512 blocks (2/CU). FROZEN (r7).
__global__ __launch_bounds__(256) void gemm_outc(
    const __hip_bfloat16* __restrict__ A,
    const __hip_bfloat16* __restrict__ B,
    const float* __restrict__ bias,
    float* __restrict__ C) {
  const int K = 1024;
  __shared__ __align__(16) __hip_bfloat16 As[64 * 32];
  __shared__ __align__(16) __hip_bfloat16 Bs[64 * 32];
  const int tid = threadIdx.x;
  const int bm = blockIdx.x * 64, bn = blockIdx.y * 64;

  const int srow = tid >> 2;          // 0..63
  const int scol = (tid & 3) * 8;     // 0,8,16,24
  const __hip_bfloat16* ap = A + (size_t)(bm + srow) * K + scol;
  const __hip_bfloat16* bp = B + (size_t)(bn + srow) * K + scol;
  __hip_bfloat16* as = &As[srow * 32 + scol];   // = LDS byte addr tid*16
  __hip_bfloat16* bs = &Bs[srow * 32 + scol];

  const int wave = tid >> 6, lane = tid & 63;
  const int wm = (wave >> 1) * 32, wn = (wave & 1) * 32;   // 2x2 waves, 32x32 each
  const int m16 = lane & 15, quad = lane >> 4;

  f32x4 acc[2][2];
#pragma unroll
  for (int i = 0; i < 2; i++)
#pragma unroll
    for (int j = 0; j < 2; j++) acc[i][j] = (f32x4)0.f;

  for (int k0 = 0; k0 < K; k0 += 32) {
    async_load16(ap + k0, as);
    async_load16(bp + k0, bs);
    __syncthreads();
    bf16x8 af[2], bfr[2];
#pragma unroll
    for (int mt = 0; mt < 2; mt++)
      af[mt] = *(const bf16x8*)&As[(wm + mt * 16 + m16) * 32 + quad * 8];
#pragma unroll
    for (int nt = 0; nt < 2; nt++)
      bfr[nt] = *(const bf16x8*)&Bs[(wn + nt * 16 + m16) * 32 + quad * 8];
#pragma unroll
    for (int mt = 0; mt < 2; mt++)
#pragma unroll
      for (int nt = 0; nt < 2; nt++)
        acc[mt][nt] = __builtin_amdgcn_mfma_f32_16x16x32_bf16(af[mt], bfr[nt], acc[mt][nt], 0, 0, 0);
    __syncthreads();
  }

#pragma unroll
  for (int mt = 0; mt < 2; mt++) {
#pragma unroll
    for (int nt = 0; nt < 2; nt++) {
      int col = bn + wn + nt * 16 + m16;
      float bv = bias[col];
#pragma unroll
      for (int r = 0; r < 4; r++) {
        int row = bm + wm + mt * 16 + quad * 4 + r;
        C[(size_t)row * 1024 + col] = acc[mt][nt][r] + bv;
      }
    }
  }
}

// ---------------- gather: d_out[b,n,:] = outc[b*512+fidx(n),:], float4 stream ----------------
__global__ __launch_bounds__(256) void gather_out_kernel(
    const float* __restrict__ outc, float* __restrict__ out) {
  const int row = blockIdx.x;            // b*4096 + n
  const int b = row >> 12, n = row & (NPOS - 1);
  const int g = fidx_of(n);
  const float4* src = (const float4*)(outc + ((size_t)(b * GSZ) + g) * DIM);
  float4* dst = (float4*)(out + (size_t)row * DIM);
  dst[threadIdx.x] = src[threadIdx.x];
}

// ---------------- field: segment-sum of v * ||k|| into G bins ----------------
// knorm-fused variant: phase 1 is now a 144-load f32 gather of precomputed norms
// (the 32 MB K re-read and the per-head sq-sum loop are gone).
__global__ __launch_bounds__(256) void wv_field_kernel(
    const __hip_bfloat16* __restrict__ V, const float* __restrict__ knorm,
    float* __restrict__ field) {
  const int b = blockIdx.x, g = blockIdx.y;
  int i0, i1;
  bin_range(g, i0, i1);
  int cnt = i1 - i0;                 // 1, 8 or 9
  if (cnt > 9) cnt = 9;
  __shared__ float km[9][16];        // [row][head]
  const int tid = threadIdx.x;
  if (tid < 144) {                   // phase 1: fetch ||k|| per (row, head); zero-fill r>=cnt
    int r = tid >> 4, h = tid & 15;
    km[r][h] = (r < cnt) ? knorm[(size_t)(b * NPOS + i0 + r) * 16 + h] : 0.f;
  }
  __syncthreads();
  const int c0 = tid * 4, h = tid >> 4;   // h = c0>>6
  const unsigned short* vbase = (const unsigned short*)V + (size_t)(b * NPOS + i0) * 1024 + c0;
  ushort4 vv[8];
  float ww[8];
#pragma unroll
  for (int j = 0; j < 8; ++j) {
    int jc = (j < cnt) ? j : 0;           // clamp: valid row, weight 0 below
    vv[j] = *(const ushort4*)(vbase + (size_t)jc * 1024);
    ww[j] = (j < cnt) ? km[j][h] : 0.f;
  }
  float a0 = 0.f, a1 = 0.f, a2 = 0.f, a3 = 0.f;
#pragma unroll
  for (int j = 0; j < 8; ++j) {
    a0 += ww[j] * bf2f(vv[j].x); a1 += ww[j] * bf2f(vv[j].y);
    a2 += ww[j] * bf2f(vv[j].z); a3 += ww[j] * bf2f(vv[j].w);
  }
  if (cnt == 9) {
    ushort4 v8 = *(const ushort4*)(vbase + (size_t)8 * 1024);
    float w8 = km[8][h];
    a0 += w8 * bf2f(v8.x); a1 += w8 * bf2f(v8.y);
    a2 += w8 * bf2f(v8.z); a3 += w8 * bf2f(v8.w);
  }
  *(float4*)(field + ((size_t)(b * GSZ + g)) * DIM + c0) = make_float4(a0, a1, a2, a3);
}

// ---------------- causal conv as EMA recurrence, LDS-staged (r9, FROZEN) ----------------
__global__ __launch_bounds__(256) void conv_ema_kernel(
    const float* __restrict__ field, __hip_bfloat16* __restrict__ convb) {
  const int b = blockIdx.x, h = blockIdx.y, n0 = blockIdx.z * 64;
  __shared__ float slab[128 * 64];
  const int tid = threadIdx.x;
  const float* fb = field + (size_t)b * GSZ * DIM + h * 64;
  for (int i = tid; i < 128 * 16; i += 256) {         // float4 loads, 8/thread
    int row = i >> 4, c4 = i & 15;
    int gg = (n0 + 257 + row) & (GSZ - 1);
    *(float4*)&slab[row * 64 + c4 * 4] = *(const float4*)(fb + (size_t)gg * DIM + c4 * 4);
  }
  __syncthreads();
  const float a = 0.71653131057378927f;   // exp(-1/3)
  const float w1 = 1.0f - a;
  const int c = tid & 63, sub = tid >> 6;
  const int e0 = sub * 16;                // emit slab range [e0, e0+16)
  float acc = 0.f;
#pragma unroll 4
  for (int t = e0 + 79; t >= e0 + 16; --t)            // 64-step warm-up (a^64 ~ 5e-10)
    acc = w1 * slab[t * 64 + c] + a * acc;
#pragma unroll
  for (int t = e0 + 15; t >= e0; --t) {
    acc = w1 * slab[t * 64 + c] + a * acc;
    convb[((size_t)(b * GSZ) + n0 + t) * DIM + h * 64 + c] = __float2bfloat16(acc);
  }
}

extern "C" void kernel_launch(void* const* d_in, const int* in_sizes, int n_in,
                              void* d_out, int out_size, void* d_ws, size_t ws_size,
                              hipStream_t stream) {
  (void)in_sizes; (void)n_in; (void)out_size; (void)ws_size;
  const float* x     = (const float*)d_in[0];
  // d_in[1]=q_w, d_in[2]=q_b: dead in the reference — skipped.
  const float* k_w   = (const float*)d_in[3];
  const float* k_b   = (const float*)d_in[4];
  const float* v_w   = (const float*)d_in[5];
  const float* v_b   = (const float*)d_in[6];
  const float* out_w = (const float*)d_in[7];
  const float* out_b = (const float*)d_in[8];

  char* p = (char*)d_ws;
  __hip_bfloat16* xb    = (__hip_bfloat16*)p;                                 // 32 MB (dead after gemm_kv)
  float*          outc  = (float*)p;          p += (size_t)16384 * 1024 * 2;  // aliases xb: 8 MB
  __hip_bfloat16* kvwb  = (__hip_bfloat16*)p; p += (size_t)2048 * 1024 * 2;   // 4 MB
  __hip_bfloat16* outwb = (__hip_bfloat16*)p; p += (size_t)1024 * 1024 * 2;   // 2 MB
  __hip_bfloat16* Vb    = (__hip_bfloat16*)p; p += (size_t)16384 * 1024 * 2;  // 32 MB (V only; K never materialized)
  float*          knorm = (float*)p;          p += (size_t)16384 * 16 * 4;    // 1 MB
  float*          field = (float*)p;          p += (size_t)4 * 512 * 1024 * 4;// 8 MB
  __hip_bfloat16* convb = (__hip_bfloat16*)p;                                 // 4 MB

  cast_all<<<19456, 256, 0, stream>>>(x, k_w, v_w, out_w, xb, kvwb, outwb);

  // fused K+V projection: K-half reduces to knorm in-epilogue; V-half stored bf16
  gemm_kv<<<dim3(128, 16), 256, 0, stream>>>(xb, kvwb, k_b, v_b, Vb, knorm);

  wv_field_kernel<<<dim3(4, 512), 256, 0, stream>>>(Vb, knorm, field);
  conv_ema_kernel<<<dim3(4, 16, 8), 256, 0, stream>>>(field, convb);

  // dedup'd output GEMM (2048 distinct rows, 512 blocks) then streaming gather
  gemm_outc<<<dim3(32, 16), 256, 0, stream>>>(convb, outwb, out_b, outc);
  gather_out_kernel<<<16384, 256, 0, stream>>>(outc, (float*)d_out);
}

// Round 2
// 264.069 us; speedup vs baseline: 1.0403x; 1.0083x over previous
//
#include <hip/hip_runtime.h>
#include <hip/hip_bf16.h>

// Problem constants (B=4, N=4096, D=1024, H=16, hd=64, G=512, sigma=3)
#define NPOS 4096
#define DIM  1024
#define GSZ  512

#define GAS __attribute__((address_space(1)))
#define LAS __attribute__((address_space(3)))

typedef __attribute__((ext_vector_type(8))) short bf16x8;   // 8 bf16 (4 VGPRs)
typedef __attribute__((ext_vector_type(4))) float f32x4;

__device__ __forceinline__ void async_load16(const void* g, void* l) {
  __builtin_amdgcn_global_load_lds((const GAS void*)g, (LAS void*)l, 16, 0, 0);
}

// Bit-exact replica of np: (arange(N,f32)/4095)*511 then trunc-to-int32.
__device__ __forceinline__ int fidx_of(int n) {
  return (int)(((float)n / 4095.0f) * 511.0f);
}

__device__ __forceinline__ float bf2f(unsigned short s) {
  union { unsigned u; float f; } v; v.u = ((unsigned)s) << 16; return v.f;
}

// exact [i0,i1) row-range of bin g under fidx_of
// NOTE: bins are 8 or 9 rows EXCEPT bin 511 which has exactly 1 row (n=4095).
__device__ __forceinline__ void bin_range(int g, int& i0, int& i1) {
  i0 = (g * 4095 + 510) / 511;
  while (i0 > 0 && fidx_of(i0 - 1) >= g) --i0;
  while (i0 < NPOS && fidx_of(i0) < g) ++i0;
  if (g == GSZ - 1) { i1 = NPOS; return; }
  i1 = ((g + 1) * 4095 + 510) / 511;
  while (i1 > 0 && fidx_of(i1 - 1) >= g + 1) --i1;
  while (i1 < NPOS && fidx_of(i1) < g + 1) ++i1;
}

// ---------------- all f32->bf16 casts in one launch (r9 config) ----------------
// blocks [0,16384): x ; [16384,17408): k_w ; [17408,18432): v_w ; [18432,19456): out_w
__global__ __launch_bounds__(256) void cast_all(
    const float* __restrict__ x, const float* __restrict__ kw,
    const float* __restrict__ vw, const float* __restrict__ ow,
    __hip_bfloat16* __restrict__ xb, __hip_bfloat16* __restrict__ kvwb,
    __hip_bfloat16* __restrict__ outwb) {
  int blk = blockIdx.x;
  const float* src; __hip_bfloat16* dst; int off;
  if (blk < 16384)      { src = x;  dst = xb;              off = blk; }
  else if (blk < 17408) { src = kw; dst = kvwb;            off = blk - 16384; }
  else if (blk < 18432) { src = vw; dst = kvwb + 1048576;  off = blk - 17408; }
  else                  { src = ow; dst = outwb;           off = blk - 18432; }
  int i = (off * 256 + threadIdx.x) * 4;
  float4 f = *(const float4*)(src + i);
  ushort4 o;
  __hip_bfloat16 t;
  t = __float2bfloat16(f.x); o.x = *(unsigned short*)&t;
  t = __float2bfloat16(f.y); o.y = *(unsigned short*)&t;
  t = __float2bfloat16(f.z); o.z = *(unsigned short*)&t;
  t = __float2bfloat16(f.w); o.w = *(unsigned short*)&t;
  *(ushort4*)(dst + i) = o;
}

// ================= 256x256-tile 8-phase bf16 MFMA GEMM (T2+T3+T4+T5) =================
// A: 16384 x 1024 (xb).  B: 2048 x 1024 row-major = [k_w ; v_w].
// 512 threads = 8 waves (2M x 4N), per-wave 128x64 output, BK=64, K=1024 -> 16 K-tiles.
// LDS: 2 dbuf x (A 32KB + B 32KB) = 128 KiB, 1 block/CU, 2 waves/SIMD.
// T2: XOR swizzle byte ^= (row&7)<<4 (LDS dest linear for global_load_lds;
//     SOURCE pre-swizzled; ds_read applies the same XOR -> 8 accesses/bank, optimal b128).
// T3/T4: 4 phases per K-tile {ds_read quadrant | barrier | lgkm0 | setprio+16 MFMA | barrier};
//     staging burst (8 global_load_lds) only in each tile's phase 4 (after its buffer's
//     reads are barrier-proven complete); s_waitcnt vmcnt(8) counted, never 0 in main loop.
// Epilogue identical to r1: K-blocks (by<4) reduce ||k|| in-register -> knorm;
// V-blocks store bf16 Vb. FP accumulation order identical to r1.

#define BAR()   __builtin_amdgcn_s_barrier()
#define LGKM0() do { asm volatile("s_waitcnt lgkmcnt(0)" ::: "memory"); \
                     __builtin_amdgcn_sched_barrier(0); } while (0)
#define VMW(N)  asm volatile("s_waitcnt vmcnt(" #N ")" ::: "memory")

#define STAGE(BUF, KT) do { \
    const __hip_bfloat16* ag_ = ag0 + (KT) * 64; \
    const __hip_bfloat16* bg_ = bg0 + (KT) * 64; \
    _Pragma("unroll") \
    for (int c_ = 0; c_ < 4; ++c_) { \
      async_load16(ag_ + (size_t)c_ * 65536, &As[BUF][c_ * 4096 + ldst]); \
      async_load16(bg_ + (size_t)c_ * 65536, &Bs[BUF][c_ * 4096 + ldst]); \
    } \
  } while (0)

#define LDA(BUF, MT, CB) (*(const bf16x8*)&As[BUF][abase + (MT) * 1024 + (CB)])
#define LDB(BUF, NT, CB) (*(const bf16x8*)&Bs[BUF][bbase + (NT) * 1024 + (CB)])

#define MFMA_Q(MQ, NQ, BF) do { \
    __builtin_amdgcn_s_setprio(1); \
    _Pragma("unroll") \
    for (int m_ = 0; m_ < 4; ++m_) { \
      _Pragma("unroll") \
      for (int n_ = 0; n_ < 2; ++n_) { \
        acc[(MQ)*4+m_][(NQ)*2+n_] = __builtin_amdgcn_mfma_f32_16x16x32_bf16( \
            af[m_][0], BF[n_][0], acc[(MQ)*4+m_][(NQ)*2+n_], 0, 0, 0); \
        acc[(MQ)*4+m_][(NQ)*2+n_] = __builtin_amdgcn_mfma_f32_16x16x32_bf16( \
            af[m_][1], BF[n_][1], acc[(MQ)*4+m_][(NQ)*2+n_], 0, 0, 0); \
      } \
    } \
    __builtin_amdgcn_s_setprio(0); \
  } while (0)

#define DO_TILE(BUF, KT) do { \
    /* P1: A-low (8 reads) + B-low (4 reads) -> MFMA quadrant (0,0) */ \
    _Pragma("unroll") \
    for (int m_ = 0; m_ < 4; ++m_) { af[m_][0] = LDA(BUF, m_, cb0); af[m_][1] = LDA(BUF, m_, cb1); } \
    _Pragma("unroll") \
    for (int n_ = 0; n_ < 2; ++n_) { b0f[n_][0] = LDB(BUF, n_, cb0); b0f[n_][1] = LDB(BUF, n_, cb1); } \
    BAR(); LGKM0(); \
    MFMA_Q(0, 0, b0f); \
    BAR(); \
    /* P2: B-high (4 reads) -> MFMA (0,1) */ \
    _Pragma("unroll") \
    for (int n_ = 0; n_ < 2; ++n_) { b1f[n_][0] = LDB(BUF, 2 + n_, cb0); b1f[n_][1] = LDB(BUF, 2 + n_, cb1); } \
    BAR(); LGKM0(); \
    MFMA_Q(0, 1, b1f); \
    BAR(); \
    /* P3: A-high (8 reads) -> MFMA (1,1); all BUF reads complete at this barrier */ \
    _Pragma("unroll") \
    for (int m_ = 0; m_ < 4; ++m_) { af[m_][0] = LDA(BUF, 4 + m_, cb0); af[m_][1] = LDA(BUF, 4 + m_, cb1); } \
    BAR(); LGKM0(); \
    MFMA_Q(1, 1, b1f); \
    BAR(); \
    /* P4: stage next same-buffer tile (safe: BUF reads done), MFMA (1,0), counted vmcnt */ \
    if ((KT) + 2 < 16) STAGE(BUF, (KT) + 2); \
    BAR(); \
    MFMA_Q(1, 0, b0f); \
    if ((KT) + 2 < 16) { VMW(8); } else if ((KT) == 14) { VMW(0); } \
    BAR(); \
  } while (0)

__global__ __launch_bounds__(512, 2) void gemm_kv(
    const __hip_bfloat16* __restrict__ A,
    const __hip_bfloat16* __restrict__ B,
    const float* __restrict__ k_b, const float* __restrict__ v_b,
    __hip_bfloat16* __restrict__ Vb, float* __restrict__ knorm) {
  __shared__ __align__(16) __hip_bfloat16 As[2][16384];   // 2 x 32 KB
  __shared__ __align__(16) __hip_bfloat16 Bs[2][16384];   // 2 x 32 KB
  const int tid = threadIdx.x;

  // XCD-aware bijective remap (nwg=512, 8 XCDs): each XCD owns one N-panel
  // (B panel 512 KB -> L2-resident) and streams A.
  const int l  = blockIdx.y * 64 + blockIdx.x;
  const int vv = (l & 7) * 64 + (l >> 3);
  const int bx = vv & 63, by = vv >> 6;
  const int bm = bx * 256;

  // ---- staging constants: linear LDS dest, pre-swizzled global source (rule #21) ----
  // LDS linear byte L = (c*512+t)*16 -> row r = c*64 + (t>>3); within-row byte (t&7)*16;
  // source col-byte = ((t&7)*16) ^ ((r&7)<<4); involution matched by the ds_read XOR.
  const int sb  = ((((tid & 7) * 16) ^ (((tid >> 3) & 7) << 4)) >> 1);
  const int r0  = tid >> 3;
  const __hip_bfloat16* ag0 = A + (size_t)(bm + r0) * 1024 + sb;
  const __hip_bfloat16* bg0 = B + (size_t)(by * 256 + r0) * 1024 + sb;
  const int ldst = tid * 8;          // element offset of chunk c=0 (chunk adds 4096)

  // ---- fragment addressing ----
  const int wave = tid >> 6, lane = tid & 63;
  const int wr = wave >> 2, wc = wave & 3;        // 2M x 4N waves
  const int m16 = lane & 15, quad = lane >> 4;
  const int swz  = (m16 & 7) << 4;                // byte XOR (row&7)<<4
  const int cb0  = ((quad * 16)      ^ swz) >> 1; // kh=0 element offset in 64-col row
  const int cb1  = ((quad * 16 + 64) ^ swz) >> 1; // kh=1
  const int abase = wr * 8192 + m16 * 64;         // (wr*128 + m16) * 64
  const int bbase = wc * 4096 + m16 * 64;         // (wc*64  + m16) * 64

  f32x4 acc[8][4];
#pragma unroll
  for (int i = 0; i < 8; i++)
#pragma unroll
    for (int j = 0; j < 4; j++) acc[i][j] = (f32x4)0.f;

  bf16x8 af[4][2], b0f[2][2], b1f[2][2];

  // prologue: stage tiles 0 and 1, wait the first, align
  STAGE(0, 0);
  STAGE(1, 1);
  VMW(8);
  BAR();

  for (int kt = 0; kt < 16; kt += 2) {
    DO_TILE(0, kt);
    DO_TILE(1, kt + 1);
  }

  // ---- epilogue (identical math to r1) ----
  if (by < 4) {
    // K block: reduce ||k||^2 per (row, head) in-register; head = 64-col span of wave
    const int head = by * 4 + wc;
    float bv[4];
#pragma unroll
    for (int nt = 0; nt < 4; nt++) bv[nt] = k_b[by * 256 + wc * 64 + nt * 16 + m16];
#pragma unroll
    for (int mt = 0; mt < 8; mt++) {
#pragma unroll
      for (int r = 0; r < 4; r++) {
        float s = 0.f;
#pragma unroll
        for (int nt = 0; nt < 4; nt++) {
          float t = acc[mt][nt][r] + bv[nt];
          s += t * t;
        }
        s += __shfl_xor(s, 1);
        s += __shfl_xor(s, 2);
        s += __shfl_xor(s, 4);
        s += __shfl_xor(s, 8);
        if (m16 == 0) {
          int row = bm + wr * 128 + mt * 16 + quad * 4 + r;
          knorm[(size_t)row * 16 + head] = sqrtf(s);
        }
      }
    }
  } else {
    // V block: bf16 store into Vb (row stride 1024)
    const int colb = (by - 4) * 256 + wc * 64;
#pragma unroll
    for (int mt = 0; mt < 8; mt++) {
#pragma unroll
      for (int nt = 0; nt < 4; nt++) {
        int col = colb + nt * 16 + m16;
        float bvv = v_b[col];
#pragma unroll
        for (int r = 0; r < 4; r++) {
          int row = bm + wr * 128 + mt * 16 + quad * 4 + r;
          Vb[(size_t)row * 1024 + col] = __float2bfloat16(acc[mt][nt][r] + bvv);
        }
      }
    }
  }
}

// ---------------- dedup output GEMM: outc = conv @ outw^T + bias (f32) ----------------
// M=2048, N=1024, K=1024. 64x64 tiles -> grid (32,16) = 512 blocks (2/CU). FROZEN (r7).
__global__ __launch_bounds__(256) void gemm_outc(
    const __hip_bfloat16* __restrict__ A,
    const __hip_bfloat16* __restrict__ B,
    const float* __restrict__ bias,
    float* __restrict__ C) {
  const int K = 1024;
  __shared__ __align__(16) __hip_bfloat16 Aso[64 * 32];
  __shared__ __align__(16) __hip_bfloat16 Bso[64 * 32];
  const int tid = threadIdx.x;
  const int bm = blockIdx.x * 64, bn = blockIdx.y * 64;

  const int srow = tid >> 2;          // 0..63
  const int scol = (tid & 3) * 8;     // 0,8,16,24
  const __hip_bfloat16* ap = A + (size_t)(bm + srow) * K + scol;
  const __hip_bfloat16* bp = B + (size_t)(bn + srow) * K + scol;
  __hip_bfloat16* as = &Aso[srow * 32 + scol];   // = LDS byte addr tid*16
  __hip_bfloat16* bs = &Bso[srow * 32 + scol];

  const int wave = tid >> 6, lane = tid & 63;
  const int wm = (wave >> 1) * 32, wn = (wave & 1) * 32;   // 2x2 waves, 32x32 each
  const int m16 = lane & 15, quad = lane >> 4;

  f32x4 acc[2][2];
#pragma unroll
  for (int i = 0; i < 2; i++)
#pragma unroll
    for (int j = 0; j < 2; j++) acc[i][j] = (f32x4)0.f;

  for (int k0 = 0; k0 < K; k0 += 32) {
    async_load16(ap + k0, as);
    async_load16(bp + k0, bs);
    __syncthreads();
    bf16x8 afr[2], bfr[2];
#pragma unroll
    for (int mt = 0; mt < 2; mt++)
      afr[mt] = *(const bf16x8*)&Aso[(wm + mt * 16 + m16) * 32 + quad * 8];
#pragma unroll
    for (int nt = 0; nt < 2; nt++)
      bfr[nt] = *(const bf16x8*)&Bso[(wn + nt * 16 + m16) * 32 + quad * 8];
#pragma unroll
    for (int mt = 0; mt < 2; mt++)
#pragma unroll
      for (int nt = 0; nt < 2; nt++)
        acc[mt][nt] = __builtin_amdgcn_mfma_f32_16x16x32_bf16(afr[mt], bfr[nt], acc[mt][nt], 0, 0, 0);
    __syncthreads();
  }

#pragma unroll
  for (int mt = 0; mt < 2; mt++) {
#pragma unroll
    for (int nt = 0; nt < 2; nt++) {
      int col = bn + wn + nt * 16 + m16;
      float bv = bias[col];
#pragma unroll
      for (int r = 0; r < 4; r++) {
        int row = bm + wm + mt * 16 + quad * 4 + r;
        C[(size_t)row * 1024 + col] = acc[mt][nt][r] + bv;
      }
    }
  }
}

// ---------------- gather: d_out[b,n,:] = outc[b*512+fidx(n),:], float4 stream ----------------
__global__ __launch_bounds__(256) void gather_out_kernel(
    const float* __restrict__ outc, float* __restrict__ out) {
  const int row = blockIdx.x;            // b*4096 + n
  const int b = row >> 12, n = row & (NPOS - 1);
  const int g = fidx_of(n);
  const float4* src = (const float4*)(outc + ((size_t)(b * GSZ) + g) * DIM);
  float4* dst = (float4*)(out + (size_t)row * DIM);
  dst[threadIdx.x] = src[threadIdx.x];
}

// ---------------- field: segment-sum of v * ||k|| into G bins ----------------
// knorm-fused variant: phase 1 is a 144-load f32 gather of precomputed norms.
__global__ __launch_bounds__(256) void wv_field_kernel(
    const __hip_bfloat16* __restrict__ V, const float* __restrict__ knorm,
    float* __restrict__ field) {
  const int b = blockIdx.x, g = blockIdx.y;
  int i0, i1;
  bin_range(g, i0, i1);
  int cnt = i1 - i0;                 // 1, 8 or 9
  if (cnt > 9) cnt = 9;
  __shared__ float km[9][16];        // [row][head]
  const int tid = threadIdx.x;
  if (tid < 144) {                   // phase 1: fetch ||k|| per (row, head); zero-fill r>=cnt
    int r = tid >> 4, h = tid & 15;
    km[r][h] = (r < cnt) ? knorm[(size_t)(b * NPOS + i0 + r) * 16 + h] : 0.f;
  }
  __syncthreads();
  const int c0 = tid * 4, h = tid >> 4;   // h = c0>>6
  const unsigned short* vbase = (const unsigned short*)V + (size_t)(b * NPOS + i0) * 1024 + c0;
  ushort4 vv[8];
  float ww[8];
#pragma unroll
  for (int j = 0; j < 8; ++j) {
    int jc = (j < cnt) ? j : 0;           // clamp: valid row, weight 0 below
    vv[j] = *(const ushort4*)(vbase + (size_t)jc * 1024);
    ww[j] = (j < cnt) ? km[j][h] : 0.f;
  }
  float a0 = 0.f, a1 = 0.f, a2 = 0.f, a3 = 0.f;
#pragma unroll
  for (int j = 0; j < 8; ++j) {
    a0 += ww[j] * bf2f(vv[j].x); a1 += ww[j] * bf2f(vv[j].y);
    a2 += ww[j] * bf2f(vv[j].z); a3 += ww[j] * bf2f(vv[j].w);
  }
  if (cnt == 9) {
    ushort4 v8 = *(const ushort4*)(vbase + (size_t)8 * 1024);
    float w8 = km[8][h];
    a0 += w8 * bf2f(v8.x); a1 += w8 * bf2f(v8.y);
    a2 += w8 * bf2f(v8.z); a3 += w8 * bf2f(v8.w);
  }
  *(float4*)(field + ((size_t)(b * GSZ + g)) * DIM + c0) = make_float4(a0, a1, a2, a3);
}

// ---------------- causal conv as EMA recurrence, LDS-staged (r9, FROZEN) ----------------
__global__ __launch_bounds__(256) void conv_ema_kernel(
    const float* __restrict__ field, __hip_bfloat16* __restrict__ convb) {
  const int b = blockIdx.x, h = blockIdx.y, n0 = blockIdx.z * 64;
  __shared__ float slab[128 * 64];
  const int tid = threadIdx.x;
  const float* fb = field + (size_t)b * GSZ * DIM + h * 64;
  for (int i = tid; i < 128 * 16; i += 256) {         // float4 loads, 8/thread
    int row = i >> 4, c4 = i & 15;
    int gg = (n0 + 257 + row) & (GSZ - 1);
    *(float4*)&slab[row * 64 + c4 * 4] = *(const float4*)(fb + (size_t)gg * DIM + c4 * 4);
  }
  __syncthreads();
  const float a = 0.71653131057378927f;   // exp(-1/3)
  const float w1 = 1.0f - a;
  const int c = tid & 63, sub = tid >> 6;
  const int e0 = sub * 16;                // emit slab range [e0, e0+16)
  float acc = 0.f;
#pragma unroll 4
  for (int t = e0 + 79; t >= e0 + 16; --t)            // 64-step warm-up (a^64 ~ 5e-10)
    acc = w1 * slab[t * 64 + c] + a * acc;
#pragma unroll
  for (int t = e0 + 15; t >= e0; --t) {
    acc = w1 * slab[t * 64 + c] + a * acc;
    convb[((size_t)(b * GSZ) + n0 + t) * DIM + h * 64 + c] = __float2bfloat16(acc);
  }
}

extern "C" void kernel_launch(void* const* d_in, const int* in_sizes, int n_in,
                              void* d_out, int out_size, void* d_ws, size_t ws_size,
                              hipStream_t stream) {
  (void)in_sizes; (void)n_in; (void)out_size; (void)ws_size;
  const float* x     = (const float*)d_in[0];
  // d_in[1]=q_w, d_in[2]=q_b: dead in the reference — skipped.
  const float* k_w   = (const float*)d_in[3];
  const float* k_b   = (const float*)d_in[4];
  const float* v_w   = (const float*)d_in[5];
  const float* v_b   = (const float*)d_in[6];
  const float* out_w = (const float*)d_in[7];
  const float* out_b = (const float*)d_in[8];

  char* p = (char*)d_ws;
  __hip_bfloat16* xb    = (__hip_bfloat16*)p;                                 // 32 MB (dead after gemm_kv)
  float*          outc  = (float*)p;          p += (size_t)16384 * 1024 * 2;  // aliases xb: 8 MB
  __hip_bfloat16* kvwb  = (__hip_bfloat16*)p; p += (size_t)2048 * 1024 * 2;   // 4 MB
  __hip_bfloat16* outwb = (__hip_bfloat16*)p; p += (size_t)1024 * 1024 * 2;   // 2 MB
  __hip_bfloat16* Vb    = (__hip_bfloat16*)p; p += (size_t)16384 * 1024 * 2;  // 32 MB (V only; K never materialized)
  float*          knorm = (float*)p;          p += (size_t)16384 * 16 * 4;    // 1 MB
  float*          field = (float*)p;          p += (size_t)4 * 512 * 1024 * 4;// 8 MB
  __hip_bfloat16* convb = (__hip_bfloat16*)p;                                 // 4 MB

  cast_all<<<19456, 256, 0, stream>>>(x, k_w, v_w, out_w, xb, kvwb, outwb);

  // fused K+V projection (256^2 8-phase): K-half -> knorm in-epilogue; V-half -> Vb
  gemm_kv<<<dim3(64, 8), 512, 0, stream>>>(xb, kvwb, k_b, v_b, Vb, knorm);

  wv_field_kernel<<<dim3(4, 512), 256, 0, stream>>>(Vb, knorm, field);
  conv_ema_kernel<<<dim3(4, 16, 8), 256, 0, stream>>>(field, convb);

  // dedup'd output GEMM (2048 distinct rows, 512 blocks) then streaming gather
  gemm_outc<<<dim3(32, 16), 256, 0, stream>>>(convb, outwb, out_b, outc);
  gather_out_kernel<<<16384, 256, 0, stream>>>(outc, (float*)d_out);
}

// Round 3
// 261.456 us; speedup vs baseline: 1.0507x; 1.0100x over previous
//
#include <hip/hip_runtime.h>
#include <hip/hip_bf16.h>

// Problem constants (B=4, N=4096, D=1024, H=16, hd=64, G=512, sigma=3)
#define NPOS 4096
#define DIM  1024
#define GSZ  512

#define GAS __attribute__((address_space(1)))
#define LAS __attribute__((address_space(3)))

typedef __attribute__((ext_vector_type(8))) short bf16x8;   // 8 bf16 (4 VGPRs)
typedef __attribute__((ext_vector_type(4))) float f32x4;

__device__ __forceinline__ void async_load16(const void* g, void* l) {
  __builtin_amdgcn_global_load_lds((const GAS void*)g, (LAS void*)l, 16, 0, 0);
}

// Bit-exact replica of np: (arange(N,f32)/4095)*511 then trunc-to-int32.
__device__ __forceinline__ int fidx_of(int n) {
  return (int)(((float)n / 4095.0f) * 511.0f);
}

__device__ __forceinline__ float bf2f(unsigned short s) {
  union { unsigned u; float f; } v; v.u = ((unsigned)s) << 16; return v.f;
}

// exact [i0,i1) row-range of bin g under fidx_of
// NOTE: bins are 8 or 9 rows EXCEPT bin 511 which has exactly 1 row (n=4095).
__device__ __forceinline__ void bin_range(int g, int& i0, int& i1) {
  i0 = (g * 4095 + 510) / 511;
  while (i0 > 0 && fidx_of(i0 - 1) >= g) --i0;
  while (i0 < NPOS && fidx_of(i0) < g) ++i0;
  if (g == GSZ - 1) { i1 = NPOS; return; }
  i1 = ((g + 1) * 4095 + 510) / 511;
  while (i1 > 0 && fidx_of(i1 - 1) >= g + 1) --i1;
  while (i1 < NPOS && fidx_of(i1) < g + 1) ++i1;
}

// ---------------- all f32->bf16 casts in one launch (r9 config) ----------------
// blocks [0,16384): x ; [16384,17408): k_w ; [17408,18432): v_w ; [18432,19456): out_w
__global__ __launch_bounds__(256) void cast_all(
    const float* __restrict__ x, const float* __restrict__ kw,
    const float* __restrict__ vw, const float* __restrict__ ow,
    __hip_bfloat16* __restrict__ xb, __hip_bfloat16* __restrict__ kvwb,
    __hip_bfloat16* __restrict__ outwb) {
  int blk = blockIdx.x;
  const float* src; __hip_bfloat16* dst; int off;
  if (blk < 16384)      { src = x;  dst = xb;              off = blk; }
  else if (blk < 17408) { src = kw; dst = kvwb;            off = blk - 16384; }
  else if (blk < 18432) { src = vw; dst = kvwb + 1048576;  off = blk - 17408; }
  else                  { src = ow; dst = outwb;           off = blk - 18432; }
  int i = (off * 256 + threadIdx.x) * 4;
  float4 f = *(const float4*)(src + i);
  ushort4 o;
  __hip_bfloat16 t;
  t = __float2bfloat16(f.x); o.x = *(unsigned short*)&t;
  t = __float2bfloat16(f.y); o.y = *(unsigned short*)&t;
  t = __float2bfloat16(f.z); o.z = *(unsigned short*)&t;
  t = __float2bfloat16(f.w); o.w = *(unsigned short*)&t;
  *(ushort4*)(dst + i) = o;
}

// ================= 256x256-tile 8-phase bf16 MFMA GEMM (T2+T3+T4+T5) =================
// A: 16384 x 1024 (xb).  B: 2048 x 1024 row-major = [k_w ; v_w].
// 512 threads = 8 waves (2M x 4N), per-wave 128x64 output, BK=64, K=1024 -> 16 K-tiles.
// LDS: 2 dbuf x (A 32KB + B 32KB) = 128 KiB, 1 block/CU, 2 waves/SIMD.
// r3: staging spread across phases (m201-style). Chunk-deadness proofs:
//   after P1 end-barrier (every wave did lgkmcnt(0) pre-MFMA): A chunks {0,2} +
//   B-low reads complete -> stage A0,A2 in P2;
//   after P2 end-barrier: ALL B reads complete -> stage B0..B3 in P3;
//   after P3 end-barrier: A chunks {1,3} complete -> stage A1,A3 in P4.
// vmcnt(8) once per tile at P4 (8 loads of this tile in flight; the older 8 -- needed
// by the NEXT tile's reads -- are drained). P4 pre-MFMA barrier dropped (no ds_reads).

#define BAR()   __builtin_amdgcn_s_barrier()
#define LGKM0() do { asm volatile("s_waitcnt lgkmcnt(0)" ::: "memory"); \
                     __builtin_amdgcn_sched_barrier(0); } while (0)
#define VMW(N)  asm volatile("s_waitcnt vmcnt(" #N ")" ::: "memory")

#define STAGE_A(BUF, KT, C) \
  async_load16(ag0 + (size_t)(KT) * 64 + (size_t)(C) * 65536, &As[BUF][(C) * 4096 + ldst])
#define STAGE_B(BUF, KT, C) \
  async_load16(bg0 + (size_t)(KT) * 64 + (size_t)(C) * 65536, &Bs[BUF][(C) * 4096 + ldst])

#define STAGE_FULL(BUF, KT) do { \
    _Pragma("unroll") \
    for (int c_ = 0; c_ < 4; ++c_) { \
      STAGE_A(BUF, KT, c_); \
      STAGE_B(BUF, KT, c_); \
    } \
  } while (0)

#define LDA(BUF, MT, CB) (*(const bf16x8*)&As[BUF][abase + (MT) * 1024 + (CB)])
#define LDB(BUF, NT, CB) (*(const bf16x8*)&Bs[BUF][bbase + (NT) * 1024 + (CB)])

#define MFMA_Q(MQ, NQ, BF) do { \
    __builtin_amdgcn_s_setprio(1); \
    _Pragma("unroll") \
    for (int m_ = 0; m_ < 4; ++m_) { \
      _Pragma("unroll") \
      for (int n_ = 0; n_ < 2; ++n_) { \
        acc[(MQ)*4+m_][(NQ)*2+n_] = __builtin_amdgcn_mfma_f32_16x16x32_bf16( \
            af[m_][0], BF[n_][0], acc[(MQ)*4+m_][(NQ)*2+n_], 0, 0, 0); \
        acc[(MQ)*4+m_][(NQ)*2+n_] = __builtin_amdgcn_mfma_f32_16x16x32_bf16( \
            af[m_][1], BF[n_][1], acc[(MQ)*4+m_][(NQ)*2+n_], 0, 0, 0); \
      } \
    } \
    __builtin_amdgcn_s_setprio(0); \
  } while (0)

#define DO_TILE(BUF, KT) do { \
    const bool pf_ = (KT) + 2 < 16; \
    /* P1: A-low (8 ds: chunks 0,2) + B-low (4 ds) -> MFMA (0,0) */ \
    _Pragma("unroll") \
    for (int m_ = 0; m_ < 4; ++m_) { af[m_][0] = LDA(BUF, m_, cb0); af[m_][1] = LDA(BUF, m_, cb1); } \
    _Pragma("unroll") \
    for (int n_ = 0; n_ < 2; ++n_) { b0f[n_][0] = LDB(BUF, n_, cb0); b0f[n_][1] = LDB(BUF, n_, cb1); } \
    BAR(); LGKM0(); \
    MFMA_Q(0, 0, b0f); \
    BAR(); \
    /* P2: B-high (4 ds); stage A chunks 0,2 (dead since P1 end-bar) -> MFMA (0,1) */ \
    _Pragma("unroll") \
    for (int n_ = 0; n_ < 2; ++n_) { b1f[n_][0] = LDB(BUF, 2 + n_, cb0); b1f[n_][1] = LDB(BUF, 2 + n_, cb1); } \
    if (pf_) { STAGE_A(BUF, (KT) + 2, 0); STAGE_A(BUF, (KT) + 2, 2); } \
    BAR(); LGKM0(); \
    MFMA_Q(0, 1, b1f); \
    BAR(); \
    /* P3: A-high (8 ds: chunks 1,3); stage B 0..3 (all B reads done) -> MFMA (1,1) */ \
    _Pragma("unroll") \
    for (int m_ = 0; m_ < 4; ++m_) { af[m_][0] = LDA(BUF, 4 + m_, cb0); af[m_][1] = LDA(BUF, 4 + m_, cb1); } \
    if (pf_) { STAGE_B(BUF, (KT) + 2, 0); STAGE_B(BUF, (KT) + 2, 1); \
               STAGE_B(BUF, (KT) + 2, 2); STAGE_B(BUF, (KT) + 2, 3); } \
    BAR(); LGKM0(); \
    MFMA_Q(1, 1, b1f); \
    BAR(); \
    /* P4: stage A chunks 1,3 (dead since P3 end-bar); MFMA (1,0); counted vmcnt */ \
    if (pf_) { STAGE_A(BUF, (KT) + 2, 1); STAGE_A(BUF, (KT) + 2, 3); } \
    MFMA_Q(1, 0, b0f); \
    if (pf_) { VMW(8); } else if ((KT) == 14) { VMW(0); } \
    BAR(); \
  } while (0)

__global__ __launch_bounds__(512, 2) void gemm_kv(
    const __hip_bfloat16* __restrict__ A,
    const __hip_bfloat16* __restrict__ B,
    const float* __restrict__ k_b, const float* __restrict__ v_b,
    __hip_bfloat16* __restrict__ Vb, float* __restrict__ knorm) {
  __shared__ __align__(16) __hip_bfloat16 As[2][16384];   // 2 x 32 KB
  __shared__ __align__(16) __hip_bfloat16 Bs[2][16384];   // 2 x 32 KB
  const int tid = threadIdx.x;

  // XCD-aware bijective remap (nwg=512, 8 XCDs): each XCD owns one N-panel
  // (B panel 512 KB -> L2-resident) and streams A (L3-resident).
  const int l  = blockIdx.y * 64 + blockIdx.x;
  const int vv = (l & 7) * 64 + (l >> 3);
  const int bx = vv & 63, by = vv >> 6;
  const int bm = bx * 256;

  // ---- staging constants: linear LDS dest, pre-swizzled global source (rule #21) ----
  // LDS linear byte L = (c*512+t)*16 -> row r = c*64 + (t>>3); within-row byte (t&7)*16;
  // source col-byte = ((t&7)*16) ^ ((r&7)<<4); involution matched by the ds_read XOR.
  const int sb  = ((((tid & 7) * 16) ^ (((tid >> 3) & 7) << 4)) >> 1);
  const int r0  = tid >> 3;
  const __hip_bfloat16* ag0 = A + (size_t)(bm + r0) * 1024 + sb;
  const __hip_bfloat16* bg0 = B + (size_t)(by * 256 + r0) * 1024 + sb;
  const int ldst = tid * 8;          // element offset of chunk c=0 (chunk adds 4096)

  // ---- fragment addressing ----
  const int wave = tid >> 6, lane = tid & 63;
  const int wr = wave >> 2, wc = wave & 3;        // 2M x 4N waves
  const int m16 = lane & 15, quad = lane >> 4;
  const int swz  = (m16 & 7) << 4;                // byte XOR (row&7)<<4
  const int cb0  = ((quad * 16)      ^ swz) >> 1; // kh=0 element offset in 64-col row
  const int cb1  = ((quad * 16 + 64) ^ swz) >> 1; // kh=1
  const int abase = wr * 8192 + m16 * 64;         // (wr*128 + m16) * 64
  const int bbase = wc * 4096 + m16 * 64;         // (wc*64  + m16) * 64

  f32x4 acc[8][4];
#pragma unroll
  for (int i = 0; i < 8; i++)
#pragma unroll
    for (int j = 0; j < 4; j++) acc[i][j] = (f32x4)0.f;

  bf16x8 af[4][2], b0f[2][2], b1f[2][2];

  // prologue: stage tiles 0 and 1, wait the first (8 of tile1 stay in flight)
  STAGE_FULL(0, 0);
  STAGE_FULL(1, 1);
  VMW(8);
  BAR();

  for (int kt = 0; kt < 16; kt += 2) {
    DO_TILE(0, kt);
    DO_TILE(1, kt + 1);
  }

  // ---- epilogue (identical math to r1/r2) ----
  if (by < 4) {
    // K block: reduce ||k||^2 per (row, head) in-register; head = 64-col span of wave
    const int head = by * 4 + wc;
    float bv[4];
#pragma unroll
    for (int nt = 0; nt < 4; nt++) bv[nt] = k_b[by * 256 + wc * 64 + nt * 16 + m16];
#pragma unroll
    for (int mt = 0; mt < 8; mt++) {
#pragma unroll
      for (int r = 0; r < 4; r++) {
        float s = 0.f;
#pragma unroll
        for (int nt = 0; nt < 4; nt++) {
          float t = acc[mt][nt][r] + bv[nt];
          s += t * t;
        }
        s += __shfl_xor(s, 1);
        s += __shfl_xor(s, 2);
        s += __shfl_xor(s, 4);
        s += __shfl_xor(s, 8);
        if (m16 == 0) {
          int row = bm + wr * 128 + mt * 16 + quad * 4 + r;
          knorm[(size_t)row * 16 + head] = sqrtf(s);
        }
      }
    }
  } else {
    // V block: bf16 store into Vb (row stride 1024)
    const int colb = (by - 4) * 256 + wc * 64;
#pragma unroll
    for (int mt = 0; mt < 8; mt++) {
#pragma unroll
      for (int nt = 0; nt < 4; nt++) {
        int col = colb + nt * 16 + m16;
        float bvv = v_b[col];
#pragma unroll
        for (int r = 0; r < 4; r++) {
          int row = bm + wr * 128 + mt * 16 + quad * 4 + r;
          Vb[(size_t)row * 1024 + col] = __float2bfloat16(acc[mt][nt][r] + bvv);
        }
      }
    }
  }
}

// ---------------- output GEMM fused with gather: d_out = dup(conv @ outw^T + bias) ----------------
// M=2048 distinct rows, N=1024, K=1024. 64x64 tiles -> grid (32,16) = 512 blocks.
// Epilogue writes each value directly to all 8-9 duplicated output rows of its bin
// (exact bin_range) -- eliminates the outc intermediate and the gather kernel.
__global__ __launch_bounds__(256) void gemm_outc(
    const __hip_bfloat16* __restrict__ A,
    const __hip_bfloat16* __restrict__ B,
    const float* __restrict__ bias,
    float* __restrict__ C) {
  const int K = 1024;
  __shared__ __align__(16) __hip_bfloat16 Aso[64 * 32];
  __shared__ __align__(16) __hip_bfloat16 Bso[64 * 32];
  const int tid = threadIdx.x;
  const int bm = blockIdx.x * 64, bn = blockIdx.y * 64;

  const int srow = tid >> 2;          // 0..63
  const int scol = (tid & 3) * 8;     // 0,8,16,24
  const __hip_bfloat16* ap = A + (size_t)(bm + srow) * K + scol;
  const __hip_bfloat16* bp = B + (size_t)(bn + srow) * K + scol;
  __hip_bfloat16* as = &Aso[srow * 32 + scol];   // = LDS byte addr tid*16
  __hip_bfloat16* bs = &Bso[srow * 32 + scol];

  const int wave = tid >> 6, lane = tid & 63;
  const int wm = (wave >> 1) * 32, wn = (wave & 1) * 32;   // 2x2 waves, 32x32 each
  const int m16 = lane & 15, quad = lane >> 4;

  f32x4 acc[2][2];
#pragma unroll
  for (int i = 0; i < 2; i++)
#pragma unroll
    for (int j = 0; j < 2; j++) acc[i][j] = (f32x4)0.f;

  for (int k0 = 0; k0 < K; k0 += 32) {
    async_load16(ap + k0, as);
    async_load16(bp + k0, bs);
    __syncthreads();
    bf16x8 afr[2], bfr[2];
#pragma unroll
    for (int mt = 0; mt < 2; mt++)
      afr[mt] = *(const bf16x8*)&Aso[(wm + mt * 16 + m16) * 32 + quad * 8];
#pragma unroll
    for (int nt = 0; nt < 2; nt++)
      bfr[nt] = *(const bf16x8*)&Bso[(wn + nt * 16 + m16) * 32 + quad * 8];
#pragma unroll
    for (int mt = 0; mt < 2; mt++)
#pragma unroll
      for (int nt = 0; nt < 2; nt++)
        acc[mt][nt] = __builtin_amdgcn_mfma_f32_16x16x32_bf16(afr[mt], bfr[nt], acc[mt][nt], 0, 0, 0);
    __syncthreads();
  }

  // fused scatter epilogue: value -> all n in bin (values identical to outc+gather path)
#pragma unroll
  for (int mt = 0; mt < 2; mt++) {
#pragma unroll
    for (int r = 0; r < 4; r++) {
      int row = bm + wm + mt * 16 + quad * 4 + r;   // 0..2047 = b*512 + g
      int bb = row >> 9, g = row & (GSZ - 1);
      int i0, i1;
      bin_range(g, i0, i1);
      float* obase = C + ((size_t)bb << 12) * DIM;
#pragma unroll
      for (int nt = 0; nt < 2; nt++) {
        int col = bn + wn + nt * 16 + m16;
        float val = acc[mt][nt][r] + bias[col];
        for (int n = i0; n < i1; ++n)
          obase[(size_t)n * DIM + col] = val;
      }
    }
  }
}

// ---------------- field: segment-sum of v * ||k|| into G bins ----------------
// knorm-fused variant: phase 1 is a 144-load f32 gather of precomputed norms.
__global__ __launch_bounds__(256) void wv_field_kernel(
    const __hip_bfloat16* __restrict__ V, const float* __restrict__ knorm,
    float* __restrict__ field) {
  const int b = blockIdx.x, g = blockIdx.y;
  int i0, i1;
  bin_range(g, i0, i1);
  int cnt = i1 - i0;                 // 1, 8 or 9
  if (cnt > 9) cnt = 9;
  __shared__ float km[9][16];        // [row][head]
  const int tid = threadIdx.x;
  if (tid < 144) {                   // phase 1: fetch ||k|| per (row, head); zero-fill r>=cnt
    int r = tid >> 4, h = tid & 15;
    km[r][h] = (r < cnt) ? knorm[(size_t)(b * NPOS + i0 + r) * 16 + h] : 0.f;
  }
  __syncthreads();
  const int c0 = tid * 4, h = tid >> 4;   // h = c0>>6
  const unsigned short* vbase = (const unsigned short*)V + (size_t)(b * NPOS + i0) * 1024 + c0;
  ushort4 vv[8];
  float ww[8];
#pragma unroll
  for (int j = 0; j < 8; ++j) {
    int jc = (j < cnt) ? j : 0;           // clamp: valid row, weight 0 below
    vv[j] = *(const ushort4*)(vbase + (size_t)jc * 1024);
    ww[j] = (j < cnt) ? km[j][h] : 0.f;
  }
  float a0 = 0.f, a1 = 0.f, a2 = 0.f, a3 = 0.f;
#pragma unroll
  for (int j = 0; j < 8; ++j) {
    a0 += ww[j] * bf2f(vv[j].x); a1 += ww[j] * bf2f(vv[j].y);
    a2 += ww[j] * bf2f(vv[j].z); a3 += ww[j] * bf2f(vv[j].w);
  }
  if (cnt == 9) {
    ushort4 v8 = *(const ushort4*)(vbase + (size_t)8 * 1024);
    float w8 = km[8][h];
    a0 += w8 * bf2f(v8.x); a1 += w8 * bf2f(v8.y);
    a2 += w8 * bf2f(v8.z); a3 += w8 * bf2f(v8.w);
  }
  *(float4*)(field + ((size_t)(b * GSZ + g)) * DIM + c0) = make_float4(a0, a1, a2, a3);
}

// ---------------- causal conv as EMA recurrence, LDS-staged (r9, FROZEN) ----------------
__global__ __launch_bounds__(256) void conv_ema_kernel(
    const float* __restrict__ field, __hip_bfloat16* __restrict__ convb) {
  const int b = blockIdx.x, h = blockIdx.y, n0 = blockIdx.z * 64;
  __shared__ float slab[128 * 64];
  const int tid = threadIdx.x;
  const float* fb = field + (size_t)b * GSZ * DIM + h * 64;
  for (int i = tid; i < 128 * 16; i += 256) {         // float4 loads, 8/thread
    int row = i >> 4, c4 = i & 15;
    int gg = (n0 + 257 + row) & (GSZ - 1);
    *(float4*)&slab[row * 64 + c4 * 4] = *(const float4*)(fb + (size_t)gg * DIM + c4 * 4);
  }
  __syncthreads();
  const float a = 0.71653131057378927f;   // exp(-1/3)
  const float w1 = 1.0f - a;
  const int c = tid & 63, sub = tid >> 6;
  const int e0 = sub * 16;                // emit slab range [e0, e0+16)
  float acc = 0.f;
#pragma unroll 4
  for (int t = e0 + 79; t >= e0 + 16; --t)            // 64-step warm-up (a^64 ~ 5e-10)
    acc = w1 * slab[t * 64 + c] + a * acc;
#pragma unroll
  for (int t = e0 + 15; t >= e0; --t) {
    acc = w1 * slab[t * 64 + c] + a * acc;
    convb[((size_t)(b * GSZ) + n0 + t) * DIM + h * 64 + c] = __float2bfloat16(acc);
  }
}

extern "C" void kernel_launch(void* const* d_in, const int* in_sizes, int n_in,
                              void* d_out, int out_size, void* d_ws, size_t ws_size,
                              hipStream_t stream) {
  (void)in_sizes; (void)n_in; (void)out_size; (void)ws_size;
  const float* x     = (const float*)d_in[0];
  // d_in[1]=q_w, d_in[2]=q_b: dead in the reference — skipped.
  const float* k_w   = (const float*)d_in[3];
  const float* k_b   = (const float*)d_in[4];
  const float* v_w   = (const float*)d_in[5];
  const float* v_b   = (const float*)d_in[6];
  const float* out_w = (const float*)d_in[7];
  const float* out_b = (const float*)d_in[8];

  char* p = (char*)d_ws;
  __hip_bfloat16* xb    = (__hip_bfloat16*)p;         p += (size_t)16384 * 1024 * 2;  // 32 MB (dead after gemm_kv)
  __hip_bfloat16* kvwb  = (__hip_bfloat16*)p; p += (size_t)2048 * 1024 * 2;   // 4 MB
  __hip_bfloat16* outwb = (__hip_bfloat16*)p; p += (size_t)1024 * 1024 * 2;   // 2 MB
  __hip_bfloat16* Vb    = (__hip_bfloat16*)p; p += (size_t)16384 * 1024 * 2;  // 32 MB (V only; K never materialized)
  float*          knorm = (float*)p;          p += (size_t)16384 * 16 * 4;    // 1 MB
  float*          field = (float*)p;          p += (size_t)4 * 512 * 1024 * 4;// 8 MB
  __hip_bfloat16* convb = (__hip_bfloat16*)p;                                 // 4 MB

  cast_all<<<19456, 256, 0, stream>>>(x, k_w, v_w, out_w, xb, kvwb, outwb);

  // fused K+V projection (256^2 8-phase): K-half -> knorm in-epilogue; V-half -> Vb
  gemm_kv<<<dim3(64, 8), 512, 0, stream>>>(xb, kvwb, k_b, v_b, Vb, knorm);

  wv_field_kernel<<<dim3(4, 512), 256, 0, stream>>>(Vb, knorm, field);
  conv_ema_kernel<<<dim3(4, 16, 8), 256, 0, stream>>>(field, convb);

  // output GEMM with fused bin-duplication scatter (writes d_out directly)
  gemm_outc<<<dim3(32, 16), 256, 0, stream>>>(convb, outwb, out_b, (float*)d_out);
}

// Round 4
// 243.691 us; speedup vs baseline: 1.1273x; 1.0729x over previous
//
#include <hip/hip_runtime.h>
#include <hip/hip_bf16.h>

// Problem constants (B=4, N=4096, D=1024, H=16, hd=64, G=512, sigma=3)
#define NPOS 4096
#define DIM  1024
#define GSZ  512

#define GAS __attribute__((address_space(1)))
#define LAS __attribute__((address_space(3)))

typedef __attribute__((ext_vector_type(8))) short bf16x8;   // 8 bf16 (4 VGPRs)
typedef __attribute__((ext_vector_type(4))) float f32x4;

__device__ __forceinline__ void async_load16(const void* g, void* l) {
  __builtin_amdgcn_global_load_lds((const GAS void*)g, (LAS void*)l, 16, 0, 0);
}

// Bit-exact replica of np: (arange(N,f32)/4095)*511 then trunc-to-int32.
__device__ __forceinline__ int fidx_of(int n) {
  return (int)(((float)n / 4095.0f) * 511.0f);
}

__device__ __forceinline__ float bf2f(unsigned short s) {
  union { unsigned u; float f; } v; v.u = ((unsigned)s) << 16; return v.f;
}

// exact first row of bin g under fidx_of (g in [0,512]; g>=512 -> 4096)
__device__ __forceinline__ int bin_start(int g) {
  if (g >= GSZ) return NPOS;
  int i0 = (g * 4095 + 510) / 511;
  while (i0 > 0 && fidx_of(i0 - 1) >= g) --i0;
  while (i0 < NPOS && fidx_of(i0) < g) ++i0;
  return i0;
}

// exact [i0,i1) row-range of bin g under fidx_of
// NOTE: bins are 8 or 9 rows EXCEPT bin 511 which has exactly 1 row (n=4095).
__device__ __forceinline__ void bin_range(int g, int& i0, int& i1) {
  i0 = bin_start(g);
  i1 = bin_start(g + 1);
}

// ---------------- all f32->bf16 casts in one launch (r4: 8 floats/thread) ----------------
// blocks [0,8192): x ; [8192,8704): k_w ; [8704,9216): v_w ; [9216,9728): out_w
__global__ __launch_bounds__(256) void cast_all(
    const float* __restrict__ x, const float* __restrict__ kw,
    const float* __restrict__ vw, const float* __restrict__ ow,
    __hip_bfloat16* __restrict__ xb, __hip_bfloat16* __restrict__ kvwb,
    __hip_bfloat16* __restrict__ outwb) {
  int blk = blockIdx.x;
  const float* src; __hip_bfloat16* dst; int off;
  if (blk < 8192)      { src = x;  dst = xb;              off = blk; }
  else if (blk < 8704) { src = kw; dst = kvwb;            off = blk - 8192; }
  else if (blk < 9216) { src = vw; dst = kvwb + 1048576;  off = blk - 8704; }
  else                 { src = ow; dst = outwb;           off = blk - 9216; }
  int i = (off * 256 + threadIdx.x) * 8;
  float4 f0 = *(const float4*)(src + i);
  float4 f1 = *(const float4*)(src + i + 4);
  ushort4 o0, o1;
  __hip_bfloat16 t;
  t = __float2bfloat16(f0.x); o0.x = *(unsigned short*)&t;
  t = __float2bfloat16(f0.y); o0.y = *(unsigned short*)&t;
  t = __float2bfloat16(f0.z); o0.z = *(unsigned short*)&t;
  t = __float2bfloat16(f0.w); o0.w = *(unsigned short*)&t;
  t = __float2bfloat16(f1.x); o1.x = *(unsigned short*)&t;
  t = __float2bfloat16(f1.y); o1.y = *(unsigned short*)&t;
  t = __float2bfloat16(f1.z); o1.z = *(unsigned short*)&t;
  t = __float2bfloat16(f1.w); o1.w = *(unsigned short*)&t;
  *(ushort4*)(dst + i) = o0;
  *(ushort4*)(dst + i + 4) = o1;
}

// ================= 256x256-tile 8-phase bf16 MFMA GEMM (T2+T3+T4+T5) =================
// A: 16384 x 1024 (xb).  B: 2048 x 1024 row-major = [k_w ; v_w].
// 512 threads = 8 waves (2M x 4N), per-wave 128x64 output, BK=64, K=1024 -> 16 K-tiles.
// LDS: 2 dbuf x (A 32KB + B 32KB) = 128 KiB, 1 block/CU, 2 waves/SIMD.
// r3: staging spread across phases (m201-style). Chunk-deadness proofs:
//   after P1 end-barrier (every wave did lgkmcnt(0) pre-MFMA): A chunks {0,2} +
//   B-low reads complete -> stage A0,A2 in P2;
//   after P2 end-barrier: ALL B reads complete -> stage B0..B3 in P3;
//   after P3 end-barrier: A chunks {1,3} complete -> stage A1,A3 in P4.
// vmcnt(8) once per tile at P4. P4 pre-MFMA barrier dropped (no ds_reads).
// r4: XCD remap switched to M-panel ownership (A 4MB = one XCD L2, reused
//     across all 8 by-groups; B streams 4MB once per XCD).

#define BAR()   __builtin_amdgcn_s_barrier()
#define LGKM0() do { asm volatile("s_waitcnt lgkmcnt(0)" ::: "memory"); \
                     __builtin_amdgcn_sched_barrier(0); } while (0)
#define VMW(N)  asm volatile("s_waitcnt vmcnt(" #N ")" ::: "memory")

#define STAGE_A(BUF, KT, C) \
  async_load16(ag0 + (size_t)(KT) * 64 + (size_t)(C) * 65536, &As[BUF][(C) * 4096 + ldst])
#define STAGE_B(BUF, KT, C) \
  async_load16(bg0 + (size_t)(KT) * 64 + (size_t)(C) * 65536, &Bs[BUF][(C) * 4096 + ldst])

#define STAGE_FULL(BUF, KT) do { \
    _Pragma("unroll") \
    for (int c_ = 0; c_ < 4; ++c_) { \
      STAGE_A(BUF, KT, c_); \
      STAGE_B(BUF, KT, c_); \
    } \
  } while (0)

#define LDA(BUF, MT, CB) (*(const bf16x8*)&As[BUF][abase + (MT) * 1024 + (CB)])
#define LDB(BUF, NT, CB) (*(const bf16x8*)&Bs[BUF][bbase + (NT) * 1024 + (CB)])

#define MFMA_Q(MQ, NQ, BF) do { \
    __builtin_amdgcn_s_setprio(1); \
    _Pragma("unroll") \
    for (int m_ = 0; m_ < 4; ++m_) { \
      _Pragma("unroll") \
      for (int n_ = 0; n_ < 2; ++n_) { \
        acc[(MQ)*4+m_][(NQ)*2+n_] = __builtin_amdgcn_mfma_f32_16x16x32_bf16( \
            af[m_][0], BF[n_][0], acc[(MQ)*4+m_][(NQ)*2+n_], 0, 0, 0); \
        acc[(MQ)*4+m_][(NQ)*2+n_] = __builtin_amdgcn_mfma_f32_16x16x32_bf16( \
            af[m_][1], BF[n_][1], acc[(MQ)*4+m_][(NQ)*2+n_], 0, 0, 0); \
      } \
    } \
    __builtin_amdgcn_s_setprio(0); \
  } while (0)

#define DO_TILE(BUF, KT) do { \
    const bool pf_ = (KT) + 2 < 16; \
    /* P1: A-low (8 ds: chunks 0,2) + B-low (4 ds) -> MFMA (0,0) */ \
    _Pragma("unroll") \
    for (int m_ = 0; m_ < 4; ++m_) { af[m_][0] = LDA(BUF, m_, cb0); af[m_][1] = LDA(BUF, m_, cb1); } \
    _Pragma("unroll") \
    for (int n_ = 0; n_ < 2; ++n_) { b0f[n_][0] = LDB(BUF, n_, cb0); b0f[n_][1] = LDB(BUF, n_, cb1); } \
    BAR(); LGKM0(); \
    MFMA_Q(0, 0, b0f); \
    BAR(); \
    /* P2: B-high (4 ds); stage A chunks 0,2 (dead since P1 end-bar) -> MFMA (0,1) */ \
    _Pragma("unroll") \
    for (int n_ = 0; n_ < 2; ++n_) { b1f[n_][0] = LDB(BUF, 2 + n_, cb0); b1f[n_][1] = LDB(BUF, 2 + n_, cb1); } \
    if (pf_) { STAGE_A(BUF, (KT) + 2, 0); STAGE_A(BUF, (KT) + 2, 2); } \
    BAR(); LGKM0(); \
    MFMA_Q(0, 1, b1f); \
    BAR(); \
    /* P3: A-high (8 ds: chunks 1,3); stage B 0..3 (all B reads done) -> MFMA (1,1) */ \
    _Pragma("unroll") \
    for (int m_ = 0; m_ < 4; ++m_) { af[m_][0] = LDA(BUF, 4 + m_, cb0); af[m_][1] = LDA(BUF, 4 + m_, cb1); } \
    if (pf_) { STAGE_B(BUF, (KT) + 2, 0); STAGE_B(BUF, (KT) + 2, 1); \
               STAGE_B(BUF, (KT) + 2, 2); STAGE_B(BUF, (KT) + 2, 3); } \
    BAR(); LGKM0(); \
    MFMA_Q(1, 1, b1f); \
    BAR(); \
    /* P4: stage A chunks 1,3 (dead since P3 end-bar); MFMA (1,0); counted vmcnt */ \
    if (pf_) { STAGE_A(BUF, (KT) + 2, 1); STAGE_A(BUF, (KT) + 2, 3); } \
    MFMA_Q(1, 0, b0f); \
    if (pf_) { VMW(8); } else if ((KT) == 14) { VMW(0); } \
    BAR(); \
  } while (0)

__global__ __launch_bounds__(512, 2) void gemm_kv(
    const __hip_bfloat16* __restrict__ A,
    const __hip_bfloat16* __restrict__ B,
    const float* __restrict__ k_b, const float* __restrict__ v_b,
    __hip_bfloat16* __restrict__ Vb, float* __restrict__ knorm) {
  __shared__ __align__(16) __hip_bfloat16 As[2][16384];   // 2 x 32 KB
  __shared__ __align__(16) __hip_bfloat16 Bs[2][16384];   // 2 x 32 KB
  const int tid = threadIdx.x;

  // XCD-aware bijective remap (nwg=512, 8 XCDs), r4: M-panel ownership.
  // xcd = l&7, j = l>>3; bx = 8*xcd + (j&7), by = j>>3.
  // Each XCD's A working set = 8 bx-panels = 4 MB (L2-resident), reused across
  // all by; B (4 MB) streams once per XCD. Bijective: xcd=bx>>3, j=(by<<3)|(bx&7).
  const int l   = blockIdx.y * 64 + blockIdx.x;
  const int xcd = l & 7, j = l >> 3;
  const int bx  = xcd * 8 + (j & 7), by = j >> 3;
  const int bm  = bx * 256;

  // ---- staging constants: linear LDS dest, pre-swizzled global source (rule #21) ----
  // LDS linear byte L = (c*512+t)*16 -> row r = c*64 + (t>>3); within-row byte (t&7)*16;
  // source col-byte = ((t&7)*16) ^ ((r&7)<<4); involution matched by the ds_read XOR.
  const int sb  = ((((tid & 7) * 16) ^ (((tid >> 3) & 7) << 4)) >> 1);
  const int r0  = tid >> 3;
  const __hip_bfloat16* ag0 = A + (size_t)(bm + r0) * 1024 + sb;
  const __hip_bfloat16* bg0 = B + (size_t)(by * 256 + r0) * 1024 + sb;
  const int ldst = tid * 8;          // element offset of chunk c=0 (chunk adds 4096)

  // ---- fragment addressing ----
  const int wave = tid >> 6, lane = tid & 63;
  const int wr = wave >> 2, wc = wave & 3;        // 2M x 4N waves
  const int m16 = lane & 15, quad = lane >> 4;
  const int swz  = (m16 & 7) << 4;                // byte XOR (row&7)<<4
  const int cb0  = ((quad * 16)      ^ swz) >> 1; // kh=0 element offset in 64-col row
  const int cb1  = ((quad * 16 + 64) ^ swz) >> 1; // kh=1
  const int abase = wr * 8192 + m16 * 64;         // (wr*128 + m16) * 64
  const int bbase = wc * 4096 + m16 * 64;         // (wc*64  + m16) * 64

  f32x4 acc[8][4];
#pragma unroll
  for (int i = 0; i < 8; i++)
#pragma unroll
    for (int j2 = 0; j2 < 4; j2++) acc[i][j2] = (f32x4)0.f;

  bf16x8 af[4][2], b0f[2][2], b1f[2][2];

  // prologue: stage tiles 0 and 1, wait the first (8 of tile1 stay in flight)
  STAGE_FULL(0, 0);
  STAGE_FULL(1, 1);
  VMW(8);
  BAR();

  for (int kt = 0; kt < 16; kt += 2) {
    DO_TILE(0, kt);
    DO_TILE(1, kt + 1);
  }

  // ---- epilogue (identical math to r1/r2/r3) ----
  if (by < 4) {
    // K block: reduce ||k||^2 per (row, head) in-register; head = 64-col span of wave
    const int head = by * 4 + wc;
    float bv[4];
#pragma unroll
    for (int nt = 0; nt < 4; nt++) bv[nt] = k_b[by * 256 + wc * 64 + nt * 16 + m16];
#pragma unroll
    for (int mt = 0; mt < 8; mt++) {
#pragma unroll
      for (int r = 0; r < 4; r++) {
        float s = 0.f;
#pragma unroll
        for (int nt = 0; nt < 4; nt++) {
          float t = acc[mt][nt][r] + bv[nt];
          s += t * t;
        }
        s += __shfl_xor(s, 1);
        s += __shfl_xor(s, 2);
        s += __shfl_xor(s, 4);
        s += __shfl_xor(s, 8);
        if (m16 == 0) {
          int row = bm + wr * 128 + mt * 16 + quad * 4 + r;
          knorm[(size_t)row * 16 + head] = sqrtf(s);
        }
      }
    }
  } else {
    // V block: bf16 store into Vb (row stride 1024)
    const int colb = (by - 4) * 256 + wc * 64;
#pragma unroll
    for (int mt = 0; mt < 8; mt++) {
#pragma unroll
      for (int nt = 0; nt < 4; nt++) {
        int col = colb + nt * 16 + m16;
        float bvv = v_b[col];
#pragma unroll
        for (int r = 0; r < 4; r++) {
          int row = bm + wr * 128 + mt * 16 + quad * 4 + r;
          Vb[(size_t)row * 1024 + col] = __float2bfloat16(acc[mt][nt][r] + bvv);
        }
      }
    }
  }
}

// ---------------- output GEMM fused with gather (r4: LDS-staged streamer) ----------------
// M=2048 distinct rows (= b*512+g), N=1024, K=1024. 64x64 tiles -> grid (32,16).
// Epilogue v2: stage the 64x64 f32 tile (+bias) into padded LDS, then stream the
// CONTIGUOUS output-row range [bin_start(g0), bin_start(g0+64)) with coalesced
// float4 stores and zero divergence (one flat idx loop over rows*16 chunks).
// Values bit-identical to the outc+gather path.
__global__ __launch_bounds__(256) void gemm_outc(
    const __hip_bfloat16* __restrict__ A,
    const __hip_bfloat16* __restrict__ B,
    const float* __restrict__ bias,
    float* __restrict__ C) {
  const int K = 1024;
  __shared__ __align__(16) __hip_bfloat16 Aso[64 * 32];
  __shared__ __align__(16) __hip_bfloat16 Bso[64 * 32];
  __shared__ __align__(16) float ctile[64 * 68];   // stride 68 f32: float4-aligned, bank-skewed
  const int tid = threadIdx.x;
  const int bm = blockIdx.x * 64, bn = blockIdx.y * 64;

  const int srow = tid >> 2;          // 0..63
  const int scol = (tid & 3) * 8;     // 0,8,16,24
  const __hip_bfloat16* ap = A + (size_t)(bm + srow) * K + scol;
  const __hip_bfloat16* bp = B + (size_t)(bn + srow) * K + scol;
  __hip_bfloat16* as = &Aso[srow * 32 + scol];   // = LDS byte addr tid*16
  __hip_bfloat16* bs = &Bso[srow * 32 + scol];

  const int wave = tid >> 6, lane = tid & 63;
  const int wm = (wave >> 1) * 32, wn = (wave & 1) * 32;   // 2x2 waves, 32x32 each
  const int m16 = lane & 15, quad = lane >> 4;

  f32x4 acc[2][2];
#pragma unroll
  for (int i = 0; i < 2; i++)
#pragma unroll
    for (int j = 0; j < 2; j++) acc[i][j] = (f32x4)0.f;

  for (int k0 = 0; k0 < K; k0 += 32) {
    async_load16(ap + k0, as);
    async_load16(bp + k0, bs);
    __syncthreads();
    bf16x8 afr[2], bfr[2];
#pragma unroll
    for (int mt = 0; mt < 2; mt++)
      afr[mt] = *(const bf16x8*)&Aso[(wm + mt * 16 + m16) * 32 + quad * 8];
#pragma unroll
    for (int nt = 0; nt < 2; nt++)
      bfr[nt] = *(const bf16x8*)&Bso[(wn + nt * 16 + m16) * 32 + quad * 8];
#pragma unroll
    for (int mt = 0; mt < 2; mt++)
#pragma unroll
      for (int nt = 0; nt < 2; nt++)
        acc[mt][nt] = __builtin_amdgcn_mfma_f32_16x16x32_bf16(afr[mt], bfr[nt], acc[mt][nt], 0, 0, 0);
    __syncthreads();
  }

  // stage tile (+bias) into LDS
#pragma unroll
  for (int mt = 0; mt < 2; mt++) {
#pragma unroll
    for (int nt = 0; nt < 2; nt++) {
      int lcol = wn + nt * 16 + m16;
      float bv = bias[bn + lcol];
#pragma unroll
      for (int r = 0; r < 4; r++) {
        int lrow = wm + mt * 16 + quad * 4 + r;
        ctile[lrow * 68 + lcol] = acc[mt][nt][r] + bv;
      }
    }
  }
  __syncthreads();

  // stream duplicated rows: tile covers g in [g0, g0+64) of batch b (tiles never
  // straddle the 512-row batch boundary since 64 | 512).
  const int b  = bm >> 9;
  const int g0 = bm & (GSZ - 1);
  const int n0 = bin_start(g0);
  const int n1 = bin_start(g0 + 64);      // g0+64 == 512 -> 4096
  const int total = (n1 - n0) * 16;       // 16 float4-chunks per 64-col row slice
  float* obase = C + (((size_t)b << 12)) * DIM + bn;
  for (int idx = tid; idx < total; idx += 256) {
    int n  = n0 + (idx >> 4);
    int c4 = (idx & 15) * 4;
    int lg = fidx_of(n) - g0;
    float4 v = *(const float4*)&ctile[lg * 68 + c4];
    *(float4*)(obase + (size_t)n * DIM + c4) = v;
  }
}

// ---------------- field: segment-sum of v * ||k|| into G bins ----------------
// knorm-fused variant: phase 1 is a 144-load f32 gather of precomputed norms.
__global__ __launch_bounds__(256) void wv_field_kernel(
    const __hip_bfloat16* __restrict__ V, const float* __restrict__ knorm,
    float* __restrict__ field) {
  const int b = blockIdx.x, g = blockIdx.y;
  int i0, i1;
  bin_range(g, i0, i1);
  int cnt = i1 - i0;                 // 1, 8 or 9
  if (cnt > 9) cnt = 9;
  __shared__ float km[9][16];        // [row][head]
  const int tid = threadIdx.x;
  if (tid < 144) {                   // phase 1: fetch ||k|| per (row, head); zero-fill r>=cnt
    int r = tid >> 4, h = tid & 15;
    km[r][h] = (r < cnt) ? knorm[(size_t)(b * NPOS + i0 + r) * 16 + h] : 0.f;
  }
  __syncthreads();
  const int c0 = tid * 4, h = tid >> 4;   // h = c0>>6
  const unsigned short* vbase = (const unsigned short*)V + (size_t)(b * NPOS + i0) * 1024 + c0;
  ushort4 vv[8];
  float ww[8];
#pragma unroll
  for (int j = 0; j < 8; ++j) {
    int jc = (j < cnt) ? j : 0;           // clamp: valid row, weight 0 below
    vv[j] = *(const ushort4*)(vbase + (size_t)jc * 1024);
    ww[j] = (j < cnt) ? km[j][h] : 0.f;
  }
  float a0 = 0.f, a1 = 0.f, a2 = 0.f, a3 = 0.f;
#pragma unroll
  for (int j = 0; j < 8; ++j) {
    a0 += ww[j] * bf2f(vv[j].x); a1 += ww[j] * bf2f(vv[j].y);
    a2 += ww[j] * bf2f(vv[j].z); a3 += ww[j] * bf2f(vv[j].w);
  }
  if (cnt == 9) {
    ushort4 v8 = *(const ushort4*)(vbase + (size_t)8 * 1024);
    float w8 = km[8][h];
    a0 += w8 * bf2f(v8.x); a1 += w8 * bf2f(v8.y);
    a2 += w8 * bf2f(v8.z); a3 += w8 * bf2f(v8.w);
  }
  *(float4*)(field + ((size_t)(b * GSZ + g)) * DIM + c0) = make_float4(a0, a1, a2, a3);
}

// ---------------- causal conv as EMA recurrence, LDS-staged (r9, FROZEN) ----------------
__global__ __launch_bounds__(256) void conv_ema_kernel(
    const float* __restrict__ field, __hip_bfloat16* __restrict__ convb) {
  const int b = blockIdx.x, h = blockIdx.y, n0 = blockIdx.z * 64;
  __shared__ float slab[128 * 64];
  const int tid = threadIdx.x;
  const float* fb = field + (size_t)b * GSZ * DIM + h * 64;
  for (int i = tid; i < 128 * 16; i += 256) {         // float4 loads, 8/thread
    int row = i >> 4, c4 = i & 15;
    int gg = (n0 + 257 + row) & (GSZ - 1);
    *(float4*)&slab[row * 64 + c4 * 4] = *(const float4*)(fb + (size_t)gg * DIM + c4 * 4);
  }
  __syncthreads();
  const float a = 0.71653131057378927f;   // exp(-1/3)
  const float w1 = 1.0f - a;
  const int c = tid & 63, sub = tid >> 6;
  const int e0 = sub * 16;                // emit slab range [e0, e0+16)
  float acc = 0.f;
#pragma unroll 4
  for (int t = e0 + 79; t >= e0 + 16; --t)            // 64-step warm-up (a^64 ~ 5e-10)
    acc = w1 * slab[t * 64 + c] + a * acc;
#pragma unroll
  for (int t = e0 + 15; t >= e0; --t) {
    acc = w1 * slab[t * 64 + c] + a * acc;
    convb[((size_t)(b * GSZ) + n0 + t) * DIM + h * 64 + c] = __float2bfloat16(acc);
  }
}

extern "C" void kernel_launch(void* const* d_in, const int* in_sizes, int n_in,
                              void* d_out, int out_size, void* d_ws, size_t ws_size,
                              hipStream_t stream) {
  (void)in_sizes; (void)n_in; (void)out_size; (void)ws_size;
  const float* x     = (const float*)d_in[0];
  // d_in[1]=q_w, d_in[2]=q_b: dead in the reference — skipped.
  const float* k_w   = (const float*)d_in[3];
  const float* k_b   = (const float*)d_in[4];
  const float* v_w   = (const float*)d_in[5];
  const float* v_b   = (const float*)d_in[6];
  const float* out_w = (const float*)d_in[7];
  const float* out_b = (const float*)d_in[8];

  char* p = (char*)d_ws;
  __hip_bfloat16* xb    = (__hip_bfloat16*)p;         p += (size_t)16384 * 1024 * 2;  // 32 MB (dead after gemm_kv)
  __hip_bfloat16* kvwb  = (__hip_bfloat16*)p; p += (size_t)2048 * 1024 * 2;   // 4 MB
  __hip_bfloat16* outwb = (__hip_bfloat16*)p; p += (size_t)1024 * 1024 * 2;   // 2 MB
  __hip_bfloat16* Vb    = (__hip_bfloat16*)p; p += (size_t)16384 * 1024 * 2;  // 32 MB (V only; K never materialized)
  float*          knorm = (float*)p;          p += (size_t)16384 * 16 * 4;    // 1 MB
  float*          field = (float*)p;          p += (size_t)4 * 512 * 1024 * 4;// 8 MB
  __hip_bfloat16* convb = (__hip_bfloat16*)p;                                 // 4 MB

  cast_all<<<9728, 256, 0, stream>>>(x, k_w, v_w, out_w, xb, kvwb, outwb);

  // fused K+V projection (256^2 8-phase): K-half -> knorm in-epilogue; V-half -> Vb
  gemm_kv<<<dim3(64, 8), 512, 0, stream>>>(xb, kvwb, k_b, v_b, Vb, knorm);

  wv_field_kernel<<<dim3(4, 512), 256, 0, stream>>>(Vb, knorm, field);
  conv_ema_kernel<<<dim3(4, 16, 8), 256, 0, stream>>>(field, convb);

  // output GEMM with fused bin-duplication (LDS-staged streamer, writes d_out)
  gemm_outc<<<dim3(32, 16), 256, 0, stream>>>(convb, outwb, out_b, (float*)d_out);
}